// Round 5
// baseline (458.804 us; speedup 1.0000x reference)
//
#include <hip/hip_runtime.h>

// Problem constants (from reference)
constexpr int COLS    = 8;
constexpr int BATCH   = 8192;
constexpr int D       = 128;
constexpr int NUM_EMB = 12;
constexpr int NPAIRS  = 28;

// Native vector type
typedef float floatx4 __attribute__((ext_vector_type(4)));

__device__ __forceinline__ float dot4(const floatx4 a, const floatx4 b) {
    return fmaf(a.x, b.x, fmaf(a.y, b.y, fmaf(a.z, b.z, a.w * b.w)));
}

__device__ __forceinline__ floatx4 ld4(const float* p) {
    return *reinterpret_cast<const floatx4*>(p);
}

__device__ __forceinline__ float softplus01(float x) {
    return 0.01f * ((x > 15.0f) ? x : log1pf(expf(x)));
}

// Block = 256 threads = 4 waves; each 32-lane half-wave owns one batch row.
__global__ __launch_bounds__(256, 3) void dsnas_kernel(
    const int*   __restrict__ features,   // [COLS, BATCH]
    const float* __restrict__ emb_mean,   // [COLS, NUM_EMB, D]
    const float* __restrict__ emb_std,    // [COLS, NUM_EMB, D]
    const float* __restrict__ W_nc,       // [NPAIRS, 4, 2, D]
    const float* __restrict__ W_cat,      // [NPAIRS, 2, 2*D]
    const float* __restrict__ log_alpha,  // [NPAIRS, 5]
    const float* __restrict__ noise,      // [NPAIRS, 2, BATCH, D]
    float*       __restrict__ out)        // [BATCH, 2]
{
    __shared__ int pos_s[NPAIRS];

    const int tid = threadIdx.x;

    // Hard top-1 routing per pair (argmax over 5, first-max wins)
    if (tid < NPAIRS) {
        const float* la = log_alpha + tid * 5;
        float best = la[0];
        int   bi   = 0;
        #pragma unroll
        for (int t = 1; t < 5; ++t) {
            float v = la[t];
            if (v > best) { best = v; bi = t; }
        }
        pos_s[tid] = bi;
    }
    __syncthreads();

    const int b    = blockIdx.x * 8 + (tid >> 5);  // one batch row per half-wave
    const int lane = tid & 31;
    const int d0   = lane * 4;                     // 4 consecutive dims per lane

    // Per-column mean + 0.01*softplus(std) for this row's 4 dims, in VGPRs.
    floatx4 Mv[COLS], Sv[COLS];
    #pragma unroll
    for (int i = 0; i < COLS; ++i) {
        const int fi = features[i * BATCH + b];
        const floatx4 m = ld4(emb_mean + ((size_t)(i * NUM_EMB + fi)) * D + d0);
        const floatx4 s = ld4(emb_std  + ((size_t)(i * NUM_EMB + fi)) * D + d0);
        Mv[i] = m;
        floatx4 sp;
        sp.x = softplus01(s.x);
        sp.y = softplus01(s.y);
        sp.z = softplus01(s.z);
        sp.w = softplus01(s.w);
        Sv[i] = sp;
    }

    constexpr int PI[NPAIRS] = {0,0,0,0,0,0,0, 1,1,1,1,1,1, 2,2,2,2,2, 3,3,3,3, 4,4,4, 5,5, 6};
    constexpr int PJ[NPAIRS] = {1,2,3,4,5,6,7, 2,3,4,5,6,7, 3,4,5,6,7, 4,5,6,7, 5,6,7, 6,7, 7};

    const float* nrow = noise + (size_t)b * D + d0;
    constexpr size_t KSTRIDE = (size_t)2 * BATCH * D;  // between pairs k
    constexpr size_t HSTRIDE = (size_t)BATCH * D;      // between halves

    // Depth-1 double buffer, static indices only (full unroll).
    floatx4 nb0[2], nb1[2];
    nb0[0] = ld4(nrow);
    nb1[0] = ld4(nrow + HSTRIDE);

    float acc0 = 0.0f, acc1 = 0.0f;

    #pragma unroll
    for (int k = 0; k < NPAIRS; ++k) {
        const int buf = k & 1;
        const int nxt = buf ^ 1;

        // --- routing (scalar, wave-uniform); pointer selects, NO branches ---
        const int  s    = __builtin_amdgcn_readfirstlane(pos_s[k]);
        const bool s4   = (s == 4);
        const int  smin = s < 3 ? s : 3;
        const float* bnc  = W_nc  + ((size_t)(k * 4 + smin) * 2) * D;  // [2][D]
        const float* bcat = W_cat + (size_t)k * 2 * (2 * D);           // [2][2D]
        const float* wa0 = s4 ? bcat           : bnc;
        const float* wb0 = s4 ? bcat + D       : bnc;
        const float* wa1 = s4 ? bcat + 2 * D   : bnc + D;
        const float* wb1 = s4 ? bcat + 3 * D   : bnc + D;

        // --- all VMEM in straight-line code: weights then next-pair noise ---
        const floatx4 A0 = ld4(wa0 + d0);
        const floatx4 B0 = ld4(wb0 + d0);
        const floatx4 A1 = ld4(wa1 + d0);
        const floatx4 B1 = ld4(wb1 + d0);
        if (k + 1 < NPAIRS) {
            nb0[nxt] = ld4(nrow + (size_t)(k + 1) * KSTRIDE);
            nb1[nxt] = ld4(nrow + (size_t)(k + 1) * KSTRIDE + HSTRIDE);
        }

        // --- reparameterize ---
        const int i = PI[k];
        const int j = PJ[k];
        const floatx4 n0 = nb0[buf];
        const floatx4 n1 = nb1[buf];
        floatx4 p, q;
        p.x = fmaf(Sv[i].x, n0.x, Mv[i].x);
        p.y = fmaf(Sv[i].y, n0.y, Mv[i].y);
        p.z = fmaf(Sv[i].z, n0.z, Mv[i].z);
        p.w = fmaf(Sv[i].w, n0.w, Mv[i].w);
        q.x = fmaf(Sv[j].x, n1.x, Mv[j].x);
        q.y = fmaf(Sv[j].y, n1.y, Mv[j].y);
        q.z = fmaf(Sv[j].z, n1.z, Mv[j].z);
        q.w = fmaf(Sv[j].w, n1.w, Mv[j].w);

        // --- branchless combine: compute all 4, select by s, halve ---
        // Non-cat contributes dot(0.5c,wa)+dot(0.5c,wa)=dot(c,wa);
        // cat contributes dot(p,wa)+dot(q,wb).
        floatx4 h;
        {
            const float csx = p.x + q.x, cpx = p.x * q.x;
            const float cxx = fmaxf(p.x, q.x), cnx = fminf(p.x, q.x);
            const float csy = p.y + q.y, cpy = p.y * q.y;
            const float cxy = fmaxf(p.y, q.y), cny = fminf(p.y, q.y);
            const float csz = p.z + q.z, cpz = p.z * q.z;
            const float cxz = fmaxf(p.z, q.z), cnz = fminf(p.z, q.z);
            const float csw = p.w + q.w, cpw = p.w * q.w;
            const float cxw = fmaxf(p.w, q.w), cnw = fminf(p.w, q.w);
            h.x = 0.5f * (s == 0 ? csx : s == 1 ? cpx : s == 2 ? cxx : cnx);
            h.y = 0.5f * (s == 0 ? csy : s == 1 ? cpy : s == 2 ? cxy : cny);
            h.z = 0.5f * (s == 0 ? csz : s == 1 ? cpz : s == 2 ? cxz : cnz);
            h.w = 0.5f * (s == 0 ? csw : s == 1 ? cpw : s == 2 ? cxw : cnw);
        }
        floatx4 u, v;
        u.x = s4 ? p.x : h.x;  u.y = s4 ? p.y : h.y;
        u.z = s4 ? p.z : h.z;  u.w = s4 ? p.w : h.w;
        v.x = s4 ? q.x : h.x;  v.y = s4 ? q.y : h.y;
        v.z = s4 ? q.z : h.z;  v.w = s4 ? q.w : h.w;

        acc0 += dot4(u, A0) + dot4(v, B0);
        acc1 += dot4(u, A1) + dot4(v, B1);
    }

    // Reduce across the 32 lanes of this half-wave
    #pragma unroll
    for (int m = 16; m >= 1; m >>= 1) {
        acc0 += __shfl_xor(acc0, m, 64);
        acc1 += __shfl_xor(acc1, m, 64);
    }

    if (lane == 0) {
        float2 r; r.x = acc0; r.y = acc1;
        *reinterpret_cast<float2*>(out + b * 2) = r;
    }
}

extern "C" void kernel_launch(void* const* d_in, const int* in_sizes, int n_in,
                              void* d_out, int out_size, void* d_ws, size_t ws_size,
                              hipStream_t stream) {
    const int*   features  = (const int*)  d_in[0];
    const float* emb_mean  = (const float*)d_in[1];
    const float* emb_std   = (const float*)d_in[2];
    const float* W_nc      = (const float*)d_in[3];
    const float* W_cat     = (const float*)d_in[4];
    const float* log_alpha = (const float*)d_in[5];
    const float* noise     = (const float*)d_in[6];
    float*       out       = (float*)d_out;

    dim3 grid(BATCH / 8);   // 1024 blocks
    dim3 block(256);        // 4 waves, 8 batch rows/block
    dsnas_kernel<<<grid, block, 0, stream>>>(features, emb_mean, emb_std,
                                             W_nc, W_cat, log_alpha, noise, out);
}

// Round 6
// 394.249 us; speedup vs baseline: 1.1637x; 1.1637x over previous
//
#include <hip/hip_runtime.h>

// Problem constants (from reference)
constexpr int COLS    = 8;
constexpr int BATCH   = 8192;
constexpr int D       = 128;
constexpr int NUM_EMB = 12;
constexpr int NPAIRS  = 28;

typedef float floatx4 __attribute__((ext_vector_type(4)));

__device__ __forceinline__ float dot4(const floatx4 a, const floatx4 b) {
    return fmaf(a.x, b.x, fmaf(a.y, b.y, fmaf(a.z, b.z, a.w * b.w)));
}

__device__ __forceinline__ floatx4 ld4(const float* p) {
    return *reinterpret_cast<const floatx4*>(p);
}

__device__ __forceinline__ void st4(float* p, const floatx4 v) {
    *reinterpret_cast<floatx4*>(p) = v;
}

__device__ __forceinline__ float softplus01(float x) {
    return 0.01f * ((x > 15.0f) ? x : log1pf(expf(x)));
}

// Block = 256 threads = 4 waves; each 32-lane half-wave owns one batch row.
// Weights for all 28 pairs staged in LDS once per block -> main loop has ONLY
// the 2 noise loads on vmcnt. LDS 56KB -> 2 blocks/CU (8 waves/CU).
// (256,2): VGPR allocator may use up to 256 -> no spills.
__global__ __launch_bounds__(256, 2) void dsnas_kernel(
    const int*   __restrict__ features,   // [COLS, BATCH]
    const float* __restrict__ emb_mean,   // [COLS, NUM_EMB, D]
    const float* __restrict__ emb_std,    // [COLS, NUM_EMB, D]
    const float* __restrict__ W_nc,       // [NPAIRS, 4, 2, D]
    const float* __restrict__ W_cat,      // [NPAIRS, 2, 2*D]
    const float* __restrict__ log_alpha,  // [NPAIRS, 5]
    const float* __restrict__ noise,      // [NPAIRS, 2, BATCH, D]
    float*       __restrict__ out)        // [BATCH, 2]
{
    // LDS: per pair k, 4 rows of 128 floats: [A0 | B0 | A1 | B1].
    //   cat (s==4): direct copy of W_cat[k] = [wa0 wb0 wa1 wb1]  (contrib dot(p,A)+dot(q,B))
    //   non-cat:    [wnc_row0 | 0 | wnc_row1 | 0]                 (contrib dot(c,A)+dot(q,0))
    __shared__ float wlds[NPAIRS * 512];
    __shared__ int   pos_s[NPAIRS];

    const int tid = threadIdx.x;

    // Hard top-1 routing per pair (argmax over 5, first-max wins)
    if (tid < NPAIRS) {
        const float* la = log_alpha + tid * 5;
        float best = la[0];
        int   bi   = 0;
        #pragma unroll
        for (int t = 1; t < 5; ++t) {
            float v = la[t];
            if (v > best) { best = v; bi = t; }
        }
        pos_s[tid] = bi;
    }
    __syncthreads();

    // ---- Stage selected weights into LDS (one wave per pair, round-robin) ----
    {
        const int wid    = tid >> 6;   // wave id 0..3
        const int lane64 = tid & 63;
        for (int k = wid; k < NPAIRS; k += 4) {
            const int s = pos_s[k];     // uniform across the wave
            float* dst = wlds + k * 512;
            if (s == 4) {
                const float* src = W_cat + (size_t)k * 512;  // [2][256] = 512 floats
                const int f = lane64 * 8;
                st4(dst + f,     ld4(src + f));
                st4(dst + f + 4, ld4(src + f + 4));
            } else {
                const float* src = W_nc + (size_t)(k * 4 + s) * 256;  // [2][128]
                const int f   = lane64 * 4;       // 0..252
                const int row = f >> 7;           // 0 or 1
                const int d   = f & 127;
                st4(dst + row * 256 + d, ld4(src + f));
                floatx4 z = {0.0f, 0.0f, 0.0f, 0.0f};
                st4(dst + row * 256 + 128 + d, z);   // zero the B slot
            }
        }
    }
    __syncthreads();

    const int b    = blockIdx.x * 8 + (tid >> 5);  // one batch row per half-wave
    const int lane = tid & 31;
    const int d0   = lane * 4;                     // 4 consecutive dims per lane

    // Per-column mean + 0.01*softplus(std) for this row's 4 dims, in VGPRs.
    floatx4 Mv[COLS], Sv[COLS];
    #pragma unroll
    for (int i = 0; i < COLS; ++i) {
        const int fi = features[i * BATCH + b];
        const floatx4 m = ld4(emb_mean + ((size_t)(i * NUM_EMB + fi)) * D + d0);
        const floatx4 s = ld4(emb_std  + ((size_t)(i * NUM_EMB + fi)) * D + d0);
        Mv[i] = m;
        floatx4 sp;
        sp.x = softplus01(s.x);
        sp.y = softplus01(s.y);
        sp.z = softplus01(s.z);
        sp.w = softplus01(s.w);
        Sv[i] = sp;
    }

    constexpr int PI[NPAIRS] = {0,0,0,0,0,0,0, 1,1,1,1,1,1, 2,2,2,2,2, 3,3,3,3, 4,4,4, 5,5, 6};
    constexpr int PJ[NPAIRS] = {1,2,3,4,5,6,7, 2,3,4,5,6,7, 3,4,5,6,7, 4,5,6,7, 5,6,7, 6,7, 7};

    const float* nrow = noise + (size_t)b * D + d0;
    constexpr size_t KSTRIDE = (size_t)2 * BATCH * D;  // between pairs k
    constexpr size_t HSTRIDE = (size_t)BATCH * D;      // between halves

    // Depth-1 double buffer for noise; static indices only (full unroll).
    floatx4 nb0[2], nb1[2];
    nb0[0] = ld4(nrow);
    nb1[0] = ld4(nrow + HSTRIDE);

    float acc0 = 0.0f, acc1 = 0.0f;

    #pragma unroll
    for (int k = 0; k < NPAIRS; ++k) {
        const int buf = k & 1;
        const int nxt = buf ^ 1;

        // Prefetch next pair's noise (the ONLY vmcnt traffic in this loop)
        if (k + 1 < NPAIRS) {
            nb0[nxt] = ld4(nrow + (size_t)(k + 1) * KSTRIDE);
            nb1[nxt] = ld4(nrow + (size_t)(k + 1) * KSTRIDE + HSTRIDE);
        }

        // Weights from LDS (lgkmcnt; lanes 0-31 / 32-63 broadcast same rows)
        const float* wk = wlds + k * 512 + d0;
        const floatx4 A0 = ld4(wk);
        const floatx4 B0 = ld4(wk + 128);
        const floatx4 A1 = ld4(wk + 256);
        const floatx4 B1 = ld4(wk + 384);

        // Reparameterize
        const int i = PI[k];
        const int j = PJ[k];
        const floatx4 n0 = nb0[buf];
        const floatx4 n1 = nb1[buf];
        floatx4 p, q;
        p.x = fmaf(Sv[i].x, n0.x, Mv[i].x);
        p.y = fmaf(Sv[i].y, n0.y, Mv[i].y);
        p.z = fmaf(Sv[i].z, n0.z, Mv[i].z);
        p.w = fmaf(Sv[i].w, n0.w, Mv[i].w);
        q.x = fmaf(Sv[j].x, n1.x, Mv[j].x);
        q.y = fmaf(Sv[j].y, n1.y, Mv[j].y);
        q.z = fmaf(Sv[j].z, n1.z, Mv[j].z);
        q.w = fmaf(Sv[j].w, n1.w, Mv[j].w);

        // Branchless combine; B-rows are zero for non-cat so v=q always works.
        const int  s  = __builtin_amdgcn_readfirstlane(pos_s[k]);
        const bool s4 = (s == 4);
        floatx4 c;
        c.x = s == 0 ? p.x + q.x : s == 1 ? p.x * q.x : s == 2 ? fmaxf(p.x, q.x) : fminf(p.x, q.x);
        c.y = s == 0 ? p.y + q.y : s == 1 ? p.y * q.y : s == 2 ? fmaxf(p.y, q.y) : fminf(p.y, q.y);
        c.z = s == 0 ? p.z + q.z : s == 1 ? p.z * q.z : s == 2 ? fmaxf(p.z, q.z) : fminf(p.z, q.z);
        c.w = s == 0 ? p.w + q.w : s == 1 ? p.w * q.w : s == 2 ? fmaxf(p.w, q.w) : fminf(p.w, q.w);
        floatx4 u;
        u.x = s4 ? p.x : c.x;
        u.y = s4 ? p.y : c.y;
        u.z = s4 ? p.z : c.z;
        u.w = s4 ? p.w : c.w;

        acc0 += dot4(u, A0) + dot4(q, B0);
        acc1 += dot4(u, A1) + dot4(q, B1);
    }

    // Reduce across the 32 lanes of this half-wave
    #pragma unroll
    for (int m = 16; m >= 1; m >>= 1) {
        acc0 += __shfl_xor(acc0, m, 64);
        acc1 += __shfl_xor(acc1, m, 64);
    }

    if (lane == 0) {
        float2 r; r.x = acc0; r.y = acc1;
        *reinterpret_cast<float2*>(out + b * 2) = r;
    }
}

extern "C" void kernel_launch(void* const* d_in, const int* in_sizes, int n_in,
                              void* d_out, int out_size, void* d_ws, size_t ws_size,
                              hipStream_t stream) {
    const int*   features  = (const int*)  d_in[0];
    const float* emb_mean  = (const float*)d_in[1];
    const float* emb_std   = (const float*)d_in[2];
    const float* W_nc      = (const float*)d_in[3];
    const float* W_cat     = (const float*)d_in[4];
    const float* log_alpha = (const float*)d_in[5];
    const float* noise     = (const float*)d_in[6];
    float*       out       = (float*)d_out;

    dim3 grid(BATCH / 8);   // 1024 blocks
    dim3 block(256);        // 4 waves, 8 batch rows/block
    dsnas_kernel<<<grid, block, 0, stream>>>(features, emb_mean, emb_std,
                                             W_nc, W_cat, log_alpha, noise, out);
}